// Round 16
// baseline (288.298 us; speedup 1.0000x reference)
//
#include <hip/hip_runtime.h>
#include <hip/hip_bf16.h>

#define QLEN 1024
#define KLEN 2560
#define MTOT 1536   // KLEN - QLEN
#define BSZ 2
#define NH 16
#define DH 64
#define DMODEL 1024
#define DINNER 4096

typedef short bf16x8 __attribute__((ext_vector_type(8)));
typedef float f32x4  __attribute__((ext_vector_type(4)));

__device__ __forceinline__ short f2bf(float f) {
    union { float f; unsigned u; } v; v.f = f;
    unsigned r = v.u + 0x7FFFu + ((v.u >> 16) & 1u);
    return (short)(r >> 16);
}
__device__ __forceinline__ float bf2f(short s) {
    union { unsigned u; float f; } v; v.u = ((unsigned)(unsigned short)s) << 16;
    return v.f;
}
__device__ __forceinline__ unsigned pack2(float a, float b) {
    unsigned pk;
    asm("v_cvt_pk_bf16_f32 %0, %1, %2" : "=v"(pk) : "v"(a), "v"(b));
    return pk;
}

#define GLOAD16(g, l)                                                        \
    __builtin_amdgcn_global_load_lds(                                        \
        (const __attribute__((address_space(1))) unsigned int*)(g),          \
        (__attribute__((address_space(3))) unsigned int*)(l), 16, 0, 0)

// ---------------------------------------------------------------------------
// prep_all: all input conversions/transposes in ONE launch (range dispatch).
// ---------------------------------------------------------------------------
__device__ __forceinline__ void tr_body(
    const float* __restrict__ in, short* __restrict__ out,
    int K, int N, int bx, int by, int tid, float (*ts)[65])
{
    const int k0 = by * 64, n0 = bx * 64;
    const int r = tid >> 2, cb = (tid & 3) * 16;
    #pragma unroll
    for (int u = 0; u < 16; u += 4) {
        const float4 v = *(const float4*)(in + (size_t)(k0 + r) * N + n0 + cb + u);
        ts[r][cb + u] = v.x; ts[r][cb + u + 1] = v.y;
        ts[r][cb + u + 2] = v.z; ts[r][cb + u + 3] = v.w;
    }
    __syncthreads();
    #pragma unroll
    for (int p = 0; p < 4; p++) {
        const int wr_ = (tid >> 4) + p * 16;
        const int c   = (tid & 15) * 4;
        uint2 pk;
        pk.x = pack2(ts[c][wr_], ts[c + 1][wr_]);
        pk.y = pack2(ts[c + 2][wr_], ts[c + 3][wr_]);
        *(uint2*)(out + (size_t)(n0 + wr_) * K + k0 + c) = pk;
    }
}

__global__ __launch_bounds__(256) void prep_all(
    const float* __restrict__ mem, const float* __restrict__ cmem,
    const float* __restrict__ inp, short* __restrict__ catb,
    const float* __restrict__ pos, short* __restrict__ posb,
    const float* __restrict__ qkv_w, short* __restrict__ qkv_wt,
    const float* __restrict__ r_w, short* __restrict__ r_wt,
    const float* __restrict__ o_w, short* __restrict__ o_wt,
    const float* __restrict__ ff_w1, short* __restrict__ ff1t,
    const float* __restrict__ ff_w2, short* __restrict__ ff2t)
{
    __shared__ float ts[64][65];
    const int bid = blockIdx.x;
    const int tid = threadIdx.x;
    if (bid < 2560) {
        const int i = bid * 256 + tid;
        const int row = i >> 7, c = (i & 127) * 8;
        const float* src;
        if (row < 2048)      src = mem  + (size_t)row * 1024;
        else if (row < 3072) src = cmem + (size_t)(row - 2048) * 1024;
        else                 src = inp  + (size_t)(row - 3072) * 1024;
        const float4 a = *(const float4*)(src + c);
        const float4 b = *(const float4*)(src + c + 4);
        uint4 o;
        o.x = pack2(a.x, a.y); o.y = pack2(a.z, a.w);
        o.z = pack2(b.x, b.y); o.w = pack2(b.z, b.w);
        *(uint4*)(catb + (size_t)i * 8) = o;
    } else if (bid < 3840) {
        const int i = (bid - 2560) * 256 + tid;
        const float4 a = *(const float4*)(pos + (size_t)i * 8);
        const float4 b = *(const float4*)(pos + (size_t)i * 8 + 4);
        uint4 o;
        o.x = pack2(a.x, a.y); o.y = pack2(a.z, a.w);
        o.z = pack2(b.x, b.y); o.w = pack2(b.z, b.w);
        *(uint4*)(posb + (size_t)i * 8) = o;
    } else if (bid < 4608) {
        const int r = bid - 3840; tr_body(qkv_w, qkv_wt, 1024, 3072, r % 48, r / 48, tid, ts);
    } else if (bid < 4864) {
        const int r = bid - 4608; tr_body(r_w, r_wt, 1024, 1024, r % 16, r / 16, tid, ts);
    } else if (bid < 5120) {
        const int r = bid - 4864; tr_body(o_w, o_wt, 1024, 1024, r % 16, r / 16, tid, ts);
    } else if (bid < 6144) {
        const int r = bid - 5120; tr_body(ff_w1, ff1t, 1024, 4096, r % 64, r / 64, tid, ts);
    } else {
        const int r = bid - 6144; tr_body(ff_w2, ff2t, 4096, 1024, r % 16, r / 16, tid, ts);
    }
}

// whb V-part (key-major) -> vtb (BSZ*NH, DH, KLEN) key-minor. Grid (40, 32).
__global__ __launch_bounds__(256) void vt_conv(
    const short* __restrict__ wh, short* __restrict__ vt)
{
    __shared__ short Ts[64][72];
    const int j0 = blockIdx.x * 64;
    const int bn = blockIdx.y;
    const int b = bn >> 4, n = bn & 15;
    const int tid = threadIdx.x;
    {
        const int key = tid >> 2, c = (tid & 3) * 16;
        const short* p = wh + ((size_t)(j0 + key) * BSZ + b) * 3072 + 2048 + n * 64 + c;
        *(bf16x8*)&Ts[key][c]     = *(const bf16x8*)p;
        *(bf16x8*)&Ts[key][c + 8] = *(const bf16x8*)(p + 8);
    }
    __syncthreads();
    {
        const int d = tid >> 2, kc = (tid & 3) * 16;
        __attribute__((aligned(16))) short tmp[16];
        #pragma unroll
        for (int u = 0; u < 16; u++) tmp[u] = Ts[kc + u][d];
        short* q = vt + ((size_t)(bn * 64) + d) * KLEN + j0 + kc;
        *(uint4*)q       = *(uint4*)tmp;
        *(uint4*)(q + 8) = *((uint4*)tmp + 1);
    }
}

// ---------------------------------------------------------------------------
// m97 GEMM core, 2-phase pipelined (round-13 proven version): double-buffered
// LDS (32 KB -> 5 blocks/CU), next-tile global_load_lds issued BEFORE current
// ds_read+MFMA, ONE drain-barrier per K-step.
// ---------------------------------------------------------------------------
__device__ __forceinline__ void gemm_core(
    const short* __restrict__ A, const short* __restrict__ Bt,
    short* As, short* Bs, int Kfull, int klen, int bm, int bn,
    int tid, f32x4 acc[4][4])
{
    const int w  = tid >> 6;
    const int l  = tid & 63;
    const int lg = l >> 4, lc = l & 15;
    const int wr = w >> 1, wc = w & 1;
    const int srow = 2 * w * 16 + (l >> 2);
    const int scol = (l & 3) * 8;
    const size_t aoff0 = (size_t)(bm + srow) * Kfull + scol;
    const size_t boff0 = (size_t)(bn + srow) * Kfull + scol;
    const size_t rstep = (size_t)16 * Kfull;
    const int ch0 = 2 * w * 512, ch1 = (2 * w + 1) * 512;

    GLOAD16(A + aoff0, As + ch0);
    GLOAD16(A + aoff0 + rstep, As + ch1);
    GLOAD16(Bt + boff0, Bs + ch0);
    GLOAD16(Bt + boff0 + rstep, Bs + ch1);
    __syncthreads();

    int cur = 0;
    for (int k0 = 0; k0 < klen; k0 += 32) {
        const int nb = (cur ^ 1) * 4096;
        if (k0 + 32 < klen) {
            GLOAD16(A + aoff0 + k0 + 32, As + nb + ch0);
            GLOAD16(A + aoff0 + rstep + k0 + 32, As + nb + ch1);
            GLOAD16(Bt + boff0 + k0 + 32, Bs + nb + ch0);
            GLOAD16(Bt + boff0 + rstep + k0 + 32, Bs + nb + ch1);
        }
        const int cb = cur * 4096;
        bf16x8 af[4], bfr[4];
        #pragma unroll
        for (int m = 0; m < 4; m++)
            af[m] = *(const bf16x8*)(As + cb + (wr * 64 + m * 16 + lc) * 32 + lg * 8);
        #pragma unroll
        for (int n = 0; n < 4; n++)
            bfr[n] = *(const bf16x8*)(Bs + cb + (wc * 64 + n * 16 + lc) * 32 + lg * 8);
        #pragma unroll
        for (int m = 0; m < 4; m++)
            #pragma unroll
            for (int n = 0; n < 4; n++)
                acc[m][n] = __builtin_amdgcn_mfma_f32_16x16x32_bf16(
                    af[m], bfr[n], acc[m][n], 0, 0, 0);
        __syncthreads();
        cur ^= 1;
    }
}

// G1 (w_heads) + G2 (r_k) in one launch, XCD-swizzled (928 = 8*116).
__global__ __launch_bounds__(256) void gemm_g12(
    const short* __restrict__ catb, const short* __restrict__ qkv_wt,
    short* __restrict__ whb,
    const short* __restrict__ posb, const short* __restrict__ r_wt,
    short* __restrict__ rkb)
{
    __shared__ short As[8192], Bs[8192];
    const int tid = threadIdx.x;
    const int id0 = blockIdx.x;
    int id = (id0 & 7) * 116 + (id0 >> 3);   // XCD-group swizzle
    const short *A, *Bt; short* Cb; int N, bm, bn;
    if (id < 384) {
        A = catb; Bt = qkv_wt; Cb = whb; N = 3072;
        bm = (id >> 4) * 128; bn = (8 + (id & 15)) * 128;
    } else if (id < 768) {
        id -= 384;
        A = catb; Bt = qkv_wt; Cb = whb; N = 3072;
        bm = (24 + id / 24) * 128; bn = (id % 24) * 128;
    } else {
        id -= 768;
        A = posb; Bt = r_wt; Cb = rkb; N = 1024;
        bm = (id / 8) * 128; bn = (id % 8) * 128;
    }

    f32x4 acc[4][4];
    #pragma unroll
    for (int m = 0; m < 4; m++)
        #pragma unroll
        for (int n = 0; n < 4; n++) acc[m][n] = (f32x4){0.f, 0.f, 0.f, 0.f};
    gemm_core(A, Bt, As, Bs, 1024, 1024, bm, bn, tid, acc);

    const int w = tid >> 6, l = tid & 63, lg = l >> 4, lc = l & 15;
    const int wr = w >> 1, wc = w & 1;
    #pragma unroll
    for (int m = 0; m < 4; m++)
        #pragma unroll
        for (int n = 0; n < 4; n++) {
            const int col = bn + wc * 64 + n * 16 + lc;
            #pragma unroll
            for (int r = 0; r < 4; r++) {
                const int row = bm + wr * 64 + m * 16 + lg * 4 + r;
                Cb[(size_t)row * N + col] = f2bf(acc[m][n][r]);
            }
        }
}

// G7: h1 = relu(ares @ ff_w1 + b1), bf16 out. 1D grid, XCD-swizzled.
__global__ __launch_bounds__(256) void gemm_relu(
    const short* __restrict__ A, const short* __restrict__ Bt,
    const float* __restrict__ bias, short* __restrict__ Cb,
    int N, int K)
{
    __shared__ short As[8192], Bs[8192];
    const int tid = threadIdx.x;
    const int nbx = N >> 7;
    const int lid = blockIdx.x;
    const int nwg8 = gridDim.x >> 3;
    const int swz = (lid & 7) * nwg8 + (lid >> 3);
    const int bn = (swz % nbx) * 128, bm = (swz / nbx) * 128;
    f32x4 acc[4][4];
    #pragma unroll
    for (int m = 0; m < 4; m++)
        #pragma unroll
        for (int n = 0; n < 4; n++) acc[m][n] = (f32x4){0.f, 0.f, 0.f, 0.f};
    gemm_core(A, Bt, As, Bs, K, K, bm, bn, tid, acc);

    const int w = tid >> 6, l = tid & 63, lg = l >> 4, lc = l & 15;
    const int wr = w >> 1, wc = w & 1;
    #pragma unroll
    for (int m = 0; m < 4; m++)
        #pragma unroll
        for (int n = 0; n < 4; n++) {
            const int col = bn + wc * 64 + n * 16 + lc;
            const float bv = bias[col];
            #pragma unroll
            for (int r = 0; r < 4; r++) {
                const int row = bm + wr * 64 + m * 16 + lg * 4 + r;
                Cb[(size_t)row * N + col] = f2bf(fmaxf(acc[m][n][r] + bv, 0.0f));
            }
        }
}

// Split-K GEMM partial (1D grid, XCD-swizzled): z computes K-range
// [z*Ksub,(z+1)*Ksub) -> f32 partial C0/C1. nbx = N/128, nby = 16 (M=2048).
__global__ __launch_bounds__(256) void gemm_split(
    const short* __restrict__ A, const short* __restrict__ Bt,
    float* __restrict__ C0, float* __restrict__ C1,
    int N, int Kfull, int Ksub)
{
    __shared__ short As[8192], Bs[8192];
    const int tid = threadIdx.x;
    const int nbx = N >> 7;
    const int lid = blockIdx.x;
    const int nwg8 = gridDim.x >> 3;
    const int swz = (lid & 7) * nwg8 + (lid >> 3);
    const int bn = (swz % nbx) * 128;
    const int rest = swz / nbx;
    const int bm = (rest & 15) * 128;
    const int z = rest >> 4;
    float* C = z ? C1 : C0;
    f32x4 acc[4][4];
    #pragma unroll
    for (int m = 0; m < 4; m++)
        #pragma unroll
        for (int n = 0; n < 4; n++) acc[m][n] = (f32x4){0.f, 0.f, 0.f, 0.f};
    gemm_core(A + z * Ksub, Bt + z * Ksub, As, Bs, Kfull, Ksub, bm, bn, tid, acc);

    const int w = tid >> 6, l = tid & 63, lg = l >> 4, lc = l & 15;
    const int wr = w >> 1, wc = w & 1;
    #pragma unroll
    for (int m = 0; m < 4; m++)
        #pragma unroll
        for (int n = 0; n < 4; n++) {
            const int col = bn + wc * 64 + n * 16 + lc;
            #pragma unroll
            for (int r = 0; r < 4; r++) {
                const int row = bm + wr * 64 + m * 16 + lg * 4 + r;
                C[(size_t)row * N + col] = acc[m][n][r];
            }
        }
}

// ---------------------------------------------------------------------------
// MFMA flash attention — round-15 structure. ONLY change: 5-shfl rel-shift
// gather (v1 of jt == v0 of jt+1 -> hoist sh[0..4]), isolating the algebraic
// half of round 12's bundle. Removes 12 of 32 ds_bpermute per tile per lane
// on the measured LDS-pipe-bound critical path. exp2-fold NOT reapplied.
// ---------------------------------------------------------------------------
__global__ __launch_bounds__(512, 2) void attn_mfma(
    const short* __restrict__ wh,   // (KLEN*BSZ, 3072) bf16
    const short* __restrict__ vt,   // (BSZ*NH, DH, KLEN) bf16
    const short* __restrict__ rk,   // (KLEN, NH*DH) bf16
    const float* __restrict__ rwb,
    const float* __restrict__ rrb,
    short* __restrict__ po,         // (2, 256, 128, 64) bf16
    float* __restrict__ ml)         // (2, 256, 128, 2) f32
{
    __shared__ __align__(16) short Ks[2][64 * 64];  // 16 KB dbuf
    __shared__ __align__(16) short Vs[2][64 * 64];  // 16 KB dbuf [d][key]
    __shared__ __align__(16) short Rs[256 * 64];    // 32 KB ring, slot = m & 255
    __shared__ __align__(16) short Ps[8][16 * 64];  // 16 KB

    const int bid = blockIdx.x;
    const int ibp = (bid >> 3) & 7;
    const int z   = (bid >> 6) & 1;
    const int bn  = ((bid & 7) << 2) | (bid >> 7);
    const int i0  = ibp * 128;
    const int b   = bn >> 4, n = bn & 15;
    const int tid = threadIdx.x;
    const int w   = tid >> 6;        // 0..7
    const int l   = tid & 63;
    const int lg  = l >> 4;
    const int lc  = l & 15;
    const int i_base = i0 + 16 * w;

    bf16x8 aqw[2], aqr[2];
    {
        const int i = i_base + lc;
        const short* qp = wh + ((size_t)(MTOT + i) * BSZ + b) * 3072 + n * 64;
        #pragma unroll
        for (int kc2 = 0; kc2 < 2; kc2++) {
            const bf16x8 q8 = *(const bf16x8*)(qp + kc2 * 32 + lg * 8);
            const int d0 = kc2 * 32 + lg * 8;
            #pragma unroll
            for (int e = 0; e < 8; e++) {
                const float qv = bf2f(q8[e]);
                aqw[kc2][e] = f2bf(qv + rwb[n * 64 + d0 + e]);
                aqr[kc2][e] = f2bf(qv + rrb[n * 64 + d0 + e]);
            }
        }
    }

    f32x4 o_acc[4];
    #pragma unroll
    for (int nt = 0; nt < 4; nt++) o_acc[nt] = (f32x4){0.f, 0.f, 0.f, 0.f};
    float mrun[4]  = {0.f, 0.f, 0.f, 0.f};
    float lpart[4] = {0.f, 0.f, 0.f, 0.f};

    const int jend   = i0 + 1664;
    const int jhalf  = i0 / 2 + 832;       // multiple of 64; z=0 range unmasked
    const int jstart = z ? jhalf : 0;
    const int jstop  = z ? jend  : jhalf;

    const int kr = tid >> 3, kc = tid & 7;
    const size_t whK = (size_t)b * 3072 + 1024 + n * 64;
    const size_t vtK = (size_t)(bn * 64) * KLEN;
    const int mbase0 = jstart - i0 + 896;

    // prologue: ring [mbase0,+192); buf0 K/V; prefetch tile 1
    #pragma unroll
    for (int u = 0; u < 3; u++) {
        const int m = mbase0 + kr + 64 * u;
        bf16x8 rv = (bf16x8){0, 0, 0, 0, 0, 0, 0, 0};
        if (m < KLEN)
            rv = *(const bf16x8*)(rk + (size_t)m * 1024 + n * 64 + kc * 8);
        const int slot = m & 255;
        *(bf16x8*)(Rs + slot * 64 + ((kc ^ (slot & 7)) * 8)) = rv;
    }
    {
        const bf16x8 k0 = *(const bf16x8*)(wh + (size_t)(jstart + kr) * (BSZ * 3072) + whK + kc * 8);
        const bf16x8 v0 = *(const bf16x8*)(vt + vtK + (size_t)kr * KLEN + jstart + kc * 8);
        *(bf16x8*)(Ks[0] + kr * 64 + ((kc ^ (kr & 7)) * 8)) = k0;
        *(bf16x8*)(Vs[0] + kr * 64 + ((kc ^ (kr & 7)) * 8)) = v0;
    }
    bf16x8 pk = (bf16x8){0,0,0,0,0,0,0,0}, pv = pk, pr;
    {
        const int jn = jstart + 64;
        if (jn < jstop) {
            pk = *(const bf16x8*)(wh + (size_t)(jn + kr) * (BSZ * 3072) + whK + kc * 8);
            pv = *(const bf16x8*)(vt + vtK + (size_t)kr * KLEN + jn + kc * 8);
        }
        const int m = mbase0 + 192 + kr;
        pr = (m < KLEN) ? *(const bf16x8*)(rk + (size_t)m * 1024 + n * 64 + kc * 8)
                        : (bf16x8){0, 0, 0, 0, 0, 0, 0, 0};
    }

    int cur = 0;
    for (int j0 = jstart; j0 < jstop; j0 += 64) {
        const int mbase = j0 - i0 + 896;
        __syncthreads();   // all waves done with tile t-1 reads; t's buf visible
        // ---- stage tile t+1 (writes disjoint from tile t's reads) ----
        *(bf16x8*)(Ks[cur ^ 1] + kr * 64 + ((kc ^ (kr & 7)) * 8)) = pk;
        *(bf16x8*)(Vs[cur ^ 1] + kr * 64 + ((kc ^ (kr & 7)) * 8)) = pv;
        {
            const int mw = mbase + 192 + kr;
            const int slot = mw & 255;
            *(bf16x8*)(Rs + slot * 64 + ((kc ^ (slot & 7)) * 8)) = pr;
        }
        // ---- prefetch tile t+2 ----
        {
            const int jn = j0 + 128;
            if (jn < jstop) {
                pk = *(const bf16x8*)(wh + (size_t)(jn + kr) * (BSZ * 3072) + whK + kc * 8);
                pv = *(const bf16x8*)(vt + vtK + (size_t)kr * KLEN + jn + kc * 8);
            }
            const int m = mbase + 256 + kr;
            pr = (m < KLEN) ? *(const bf16x8*)(rk + (size_t)m * 1024 + n * 64 + kc * 8)
                            : (bf16x8){0, 0, 0, 0, 0, 0, 0, 0};
        }

        // ---- AC = (Q+rwb) @ K^T ----
        __builtin_amdgcn_s_setprio(1);
        f32x4 sfr[4];
        #pragma unroll
        for (int jt = 0; jt < 4; jt++) {
            const int row = 16 * jt + lc;
            const int c0 = (lg ^ (row & 7)) * 8, c1 = ((4 + lg) ^ (row & 7)) * 8;
            const bf16x8 bk0 = *(const bf16x8*)(Ks[cur] + row * 64 + c0);
            const bf16x8 bk1 = *(const bf16x8*)(Ks[cur] + row * 64 + c1);
            f32x4 acc = (f32x4){0.f, 0.f, 0.f, 0.f};
            acc = __builtin_amdgcn_mfma_f32_16x16x32_bf16(aqw[0], bk0, acc, 0, 0, 0);
            acc = __builtin_amdgcn_mfma_f32_16x16x32_bf16(aqw[1], bk1, acc, 0, 0, 0);
            sfr[jt] = acc;
        }
        // ---- Dr = (Q+rrb) @ R^T (80-row window per wave, ring slots) ----
        f32x4 dr[5];
        #pragma unroll
        for (int mt = 0; mt < 5; mt++) {
            const int slot = (mbase + 16 * mt + lc + 112 - 16 * w) & 255;
            const int c0 = (lg ^ (slot & 7)) * 8, c1 = ((4 + lg) ^ (slot & 7)) * 8;
            const bf16x8 br0 = *(const bf16x8*)(Rs + slot * 64 + c0);
            const bf16x8 br1 = *(const bf16x8*)(Rs + slot * 64 + c1);
            f32x4 acc = (f32x4){0.f, 0.f, 0.f, 0.f};
            acc = __builtin_amdgcn_mfma_f32_16x16x32_bf16(aqr[0], br0, acc, 0, 0, 0);
            acc = __builtin_amdgcn_mfma_f32_16x16x32_bf16(aqr[1], br1, acc, 0, 0, 0);
            dr[mt] = acc;
        }
        __builtin_amdgcn_s_setprio(0);

        // ---- rel-shift gather (5 shfl: v1(jt) == v0(jt+1)) + defer-max ----
        #pragma unroll
        for (int r = 0; r < 4; r++) {
            const int q   = 4 * lg + r;
            const int o   = lc + 15 - q;
            const int src = (l & 48) | (o & 15);
            float sh[5];
            #pragma unroll
            for (int t = 0; t < 5; t++) sh[t] = __shfl(dr[t][r], src);
            float sv[4];
            float mx = -1e30f;
            #pragma unroll
            for (int jt = 0; jt < 4; jt++) {
                const float bd = (o < 16) ? sh[jt] : sh[jt + 1];
                float s = (sfr[jt][r] + bd) * 0.125f;
                if (z) {
                    const int j = j0 + 16 * jt + lc;
                    if (j > i_base + q + MTOT) s = -1e30f;
                }
                sv[jt] = s;
                mx = fmaxf(mx, s);
            }
            if (__any(mx - mrun[r] > 8.0f)) {   // rare slow path
                #pragma unroll
                for (int msk = 1; msk <= 8; msk <<= 1)
                    mx = fmaxf(mx, __shfl_xor(mx, msk));
                const float mnew = fmaxf(mrun[r], mx);
                const float corr = __expf(mrun[r] - mnew);
                mrun[r] = mnew;
                lpart[r] *= corr;
                #pragma unroll
                for (int nt = 0; nt < 4; nt++) o_acc[nt][r] *= corr;
            }
            float p0 = __expf(sv[0] - mrun[r]);
            float p1 = __expf(sv[1] - mrun[r]);
            float p2 = __expf(sv[2] - mrun[r]);
            float p3 = __expf(sv[3] - mrun[r]);
            lpart[r] += (p0 + p1) + (p2 + p3);
            const unsigned pk01 = pack2(p0, p1);
            const unsigned pk23 = pack2(p2, p3);
            short* pw = Ps[w] + q * 64 + (lc & 7);
            const int qs = q & 7;
            pw[(((0 + (lc >> 3)) ^ qs) * 8)] = (short)(pk01 & 0xffffu);
            pw[(((2 + (lc >> 3)) ^ qs) * 8)] = (short)(pk01 >> 16);
            pw[(((4 + (lc >> 3)) ^ qs) * 8)] = (short)(pk23 & 0xffffu);
            pw[(((6 + (lc >> 3)) ^ qs) * 8)] = (short)(pk23 >> 16);
        }

        asm volatile("s_waitcnt lgkmcnt(0)" ::: "memory");
        __builtin_amdgcn_sched_barrier(0);

        // ---- O += P @ V ----
        __builtin_amdgcn_s_setprio(1);
        const int pc0 = (lg ^ (lc & 7)) * 8, pc1 = ((4 + lg) ^ (lc & 7)) * 8;
        const bf16x8 pa0 = *(const bf16x8*)(Ps[w] + lc * 64 + pc0);
        const bf16x8 pa1 = *(const bf16x8*)(Ps[w] + lc * 64 + pc1);
        #pragma unroll
        for (int nt = 0; nt < 4; nt++) {
            const int row = 16 * nt + lc;
            const int c0 = (lg ^ (row & 7)) * 8, c1 = ((4 + lg) ^ (row & 7)) * 8;
            const bf16x8 bv0 = *(const bf16x8*)(Vs[cur] + row * 64 + c0);
            const bf16x8 bv1 = *(const bf16x8*)(Vs[cur] + row * 64 + c1);
            o_acc[nt] = __builtin_amdgcn_mfma_f32_16x16x32_bf16(pa0, bv0, o_acc[nt], 0, 0, 0);
            o_acc[nt] = __builtin_amdgcn_mfma_f32_16x16x32_bf16(pa1, bv1, o_acc[nt], 0, 0, 0);
        }
        __builtin_amdgcn_s_setprio(0);
        cur ^= 1;
    }

    // ---- epilogue: reduce l once, write unnormalized partials ----
    const size_t blk = (size_t)z * 256 + ibp * 32 + bn;
    #pragma unroll
    for (int r = 0; r < 4; r++) {
        float lr = lpart[r];
        #pragma unroll
        for (int msk = 1; msk <= 8; msk <<= 1)
            lr += __shfl_xor(lr, msk);
        const int q = 16 * w + 4 * lg + r;    // 0..127
        #pragma unroll
        for (int nt = 0; nt < 4; nt++)
            po[(blk * 128 + q) * 64 + 16 * nt + lc] = f2bf(o_acc[nt][r]);
        if (lc == 0) {
            ml[(blk * 128 + q) * 2 + 0] = mrun[r];
            ml[(blk * 128 + q) * 2 + 1] = lr;
        }
    }
}

// Merge the two split-K partials -> attn_vec (bf16). Grid (512), 256 thr.
__global__ __launch_bounds__(256) void attn_merge(
    const short* __restrict__ po, const float* __restrict__ ml,
    short* __restrict__ av)
{
    const int blk = blockIdx.x;
    const int ib2 = blk >> 5, bn = blk & 31;
    const int b = bn >> 4, n = bn & 15;
    const int tid = threadIdx.x;
    const int q64 = tid >> 2, dc = (tid & 3) * 16;
    const int i = ib2 * 64 + q64;                       // global q row
    const size_t r0 = ((size_t)(i >> 7) * 32 + bn) * 128 + (i & 127);
    const size_t r1 = ((size_t)(256 + (i >> 7) * 32 + bn)) * 128 + (i & 127);
    const float m0 = ml[r0 * 2], l0 = ml[r0 * 2 + 1];
    const float m1 = ml[r1 * 2], l1 = ml[r1 * 2 + 1];
    const float M = fmaxf(m0, m1);
    const float c0 = __expf(m0 - M), c1 = __expf(m1 - M);
    const float invL = 1.0f / (l0 * c0 + l1 * c1);
    const bf16x8 a0 = *(const bf16x8*)(po + r0 * 64 + dc);
    const bf16x8 a1 = *(const bf16x8*)(po + r0 * 64 + dc + 8);
    const bf16x8 b0 = *(const bf16x8*)(po + r1 * 64 + dc);
    const bf16x8 b1 = *(const bf16x8*)(po + r1 * 64 + dc + 8);
    __attribute__((aligned(16))) short ov[16];
    #pragma unroll
    for (int e = 0; e < 8; e++) {
        ov[e]     = f2bf((bf2f(a0[e]) * c0 + bf2f(b0[e]) * c1) * invL);
        ov[e + 8] = f2bf((bf2f(a1[e]) * c0 + bf2f(b1[e]) * c1) * invL);
    }
    short* op = av + ((size_t)i * BSZ + b) * 1024 + n * 64 + dc;
    *(uint4*)op       = *(uint4*)ov;
    *(uint4*)(op + 8) = *((uint4*)ov + 1);
}

// ---------------------------------------------------------------------------
// Fused LayerNorm: out = LN(res + p0 + p1 (+ b2)) * scale + bias.
// OUTBF: 1 -> write bf16 only; 0 -> write f32 only.
// RESB:  residual source is bf16 (resb) instead of f32 (resf).
// ---------------------------------------------------------------------------
template <int OUTBF, bool HASB, bool RESB>
__global__ __launch_bounds__(256) void ln_fuse(
    const float* __restrict__ p0, const float* __restrict__ p1,
    const float* __restrict__ badd,
    const float* __restrict__ resf, const short* __restrict__ resb,
    const float* __restrict__ scale, const float* __restrict__ bias,
    float* __restrict__ outf, short* __restrict__ outb)
{
    const int row = blockIdx.x;
    const int tid = threadIdx.x;
    const size_t base = (size_t)row * 1024 + tid * 4;
    const float4 a = *(const float4*)(p0 + base);
    const float4 b = *(const float4*)(p1 + base);
    float rv[4];
    if (RESB) {
        const uint2 rr = *(const uint2*)(resb + base);
        rv[0] = bf2f((short)(rr.x & 0xffffu));
        rv[1] = bf2f((short)(rr.x >> 16));
        rv[2] = bf2f((short)(rr.y & 0xffffu));
        rv[3] = bf2f((short)(rr.y >> 16));
    } else {
        const float4 rf = *(const float4*)(resf + base);
        rv[0] = rf.x; rv[1] = rf.y; rv[2] = rf.z; rv[3] = rf.w;
    }
    float v[4] = {a.x + b.x + rv[0], a.y + b.y + rv[1],
                  a.z + b.z + rv[2], a.w + b.w + rv[3]};
    if (HASB) {
        const float4 bb = *(const float4*)(badd + tid * 4);
        v[0] += bb.x; v[1] += bb.y; v[2] += bb.z; v[3] += bb.w;
    }
    float s  = v[0] + v[1] + v[2] + v[3];
    float ss = v[0]*v[0] + v[1]*v[1] + v[2]*v[2] + v[3]*v[3];
    #pragma unroll
    for (int off = 32; off >= 1; off >>= 1) {
        s  += __shfl_down(s, off);
        ss += __shfl_down(ss, off);
    }
    __shared__ float red[8];
    const int lane = tid & 63, wid = tid >> 6;
    if (lane == 0) { red[wid] = s; red[4 + wid] = ss; }
    __syncthreads();
    if (tid == 0) {
        red[0] = red[0] + red[1] + red[2] + red[3];
        red[4] = red[4] + red[5] + red[6] + red[7];
    }
    __syncthreads();
    const float mean = red[0] * (1.0f / 1024.0f);
    const float var  = red[4] * (1.0f / 1024.0f) - mean * mean;
    const float rstd = rsqrtf(var + 1e-5f);
    const float4 sc = *(const float4*)(scale + tid * 4);
    const float4 bi = *(const float4*)(bias + tid * 4);
    float o0 = (v[0] - mean) * rstd * sc.x + bi.x;
    float o1 = (v[1] - mean) * rstd * sc.y + bi.y;
    float o2 = (v[2] - mean) * rstd * sc.z + bi.z;
    float o3 = (v[3] - mean) * rstd * sc.w + bi.w;
    if (OUTBF) {
        uint2 pk;
        pk.x = pack2(o0, o1);
        pk.y = pack2(o2, o3);
        *(uint2*)(outb + base) = pk;
    } else {
        *(float4*)(outf + base) = make_float4(o0, o1, o2, o3);
    }
}

// ---------------------------------------------------------------------------
extern "C" void kernel_launch(void* const* d_in, const int* in_sizes, int n_in,
                              void* d_out, int out_size, void* d_ws, size_t ws_size,
                              hipStream_t stream) {
    const float* input_ids = (const float*)d_in[0];
    const float* pos_emb   = (const float*)d_in[1];
    const float* mem       = (const float*)d_in[2];
    const float* c_mem     = (const float*)d_in[3];
    const float* qkv_w     = (const float*)d_in[5];
    const float* r_w       = (const float*)d_in[6];
    const float* o_w       = (const float*)d_in[7];
    const float* r_w_bias  = (const float*)d_in[8];
    const float* r_r_bias  = (const float*)d_in[9];
    const float* ln_a_s    = (const float*)d_in[10];
    const float* ln_a_b    = (const float*)d_in[11];
    const float* ff_w1     = (const float*)d_in[12];
    const float* ff_b1     = (const float*)d_in[13];
    const float* ff_w2     = (const float*)d_in[14];
    const float* ff_b2     = (const float*)d_in[15];
    const float* ln_f_s    = (const float*)d_in[16];
    const float* ln_f_b    = (const float*)d_in[17];

    char* base = (char*)d_ws;
    short* o_wt   = (short*)(base + 0);
    short* ff1t   = (short*)(base + 2097152);
    short* ff2t   = (short*)(base + 10485760);
    short* whb    = (short*)(base + 18874368);
    short* rkb    = (short*)(base + 50331648);
    short* qkv_wt = (short*)(base + 55574528);
    short* catb   = (short*)(base + 61865984);
    short* posb   = (short*)(base + 72351744);
    short* r_wt   = (short*)(base + 77594624);
    short* vtb    = (short*)(base + 55574528);
    short* po     = (short*)(base + 66060288);
    float* mlb    = (float*)(base + 74448896);
    short* avb    = (short*)(base + 74973184);
    float* hp0    = (float*)(base + 18874368);
    float* hp1    = (float*)(base + 27262976);
    short* aresb  = (short*)(base + 44040192);
    short* h1b    = (short*)(base + 48234496);

    const dim3 thr(256);

    prep_all<<<dim3(7168), thr, 0, stream>>>(
        mem, c_mem, input_ids, catb, pos_emb, posb,
        qkv_w, qkv_wt, r_w, r_wt, o_w, o_wt, ff_w1, ff1t, ff_w2, ff2t);
    gemm_g12<<<dim3(928), thr, 0, stream>>>(catb, qkv_wt, whb, posb, r_wt, rkb);
    vt_conv<<<dim3(40, 32), thr, 0, stream>>>(whb, vtb);
    attn_mfma<<<dim3(512), dim3(512), 0, stream>>>(
        whb, vtb, rkb, r_w_bias, r_r_bias, po, mlb);
    attn_merge<<<dim3(512), thr, 0, stream>>>(po, mlb, avb);
    gemm_split<<<dim3(256), thr, 0, stream>>>(
        avb, o_wt, hp0, hp1, 1024, 1024, 512);
    // attn_res = LN(input + hp0 + hp1) -> bf16 only
    ln_fuse<1, false, false><<<dim3(2048), thr, 0, stream>>>(
        hp0, hp1, nullptr, input_ids, nullptr, ln_a_s, ln_a_b, nullptr, aresb);
    gemm_relu<<<dim3(512), thr, 0, stream>>>(aresb, ff1t, ff_b1, h1b, 4096, 1024);
    gemm_split<<<dim3(256), thr, 0, stream>>>(
        h1b, ff2t, hp0, hp1, 1024, 4096, 2048);
    // out = LN(aresb + hp0 + hp1 + b2), residual from bf16
    ln_fuse<0, true, true><<<dim3(2048), thr, 0, stream>>>(
        hp0, hp1, ff_b2, nullptr, aresb, ln_f_s, ln_f_b, (float*)d_out, nullptr);
}

// Round 17
// 247.707 us; speedup vs baseline: 1.1639x; 1.1639x over previous
//
#include <hip/hip_runtime.h>
#include <hip/hip_bf16.h>

#define QLEN 1024
#define KLEN 2560
#define MTOT 1536   // KLEN - QLEN
#define BSZ 2
#define NH 16
#define DH 64
#define DMODEL 1024
#define DINNER 4096

typedef short bf16x8 __attribute__((ext_vector_type(8)));
typedef float f32x4  __attribute__((ext_vector_type(4)));

__device__ __forceinline__ short f2bf(float f) {
    union { float f; unsigned u; } v; v.f = f;
    unsigned r = v.u + 0x7FFFu + ((v.u >> 16) & 1u);
    return (short)(r >> 16);
}
__device__ __forceinline__ float bf2f(short s) {
    union { unsigned u; float f; } v; v.u = ((unsigned)(unsigned short)s) << 16;
    return v.f;
}
__device__ __forceinline__ unsigned pack2(float a, float b) {
    unsigned pk;
    asm("v_cvt_pk_bf16_f32 %0, %1, %2" : "=v"(pk) : "v"(a), "v"(b));
    return pk;
}

#define GLOAD16(g, l)                                                        \
    __builtin_amdgcn_global_load_lds(                                        \
        (const __attribute__((address_space(1))) unsigned int*)(g),          \
        (__attribute__((address_space(3))) unsigned int*)(l), 16, 0, 0)

// ---------------------------------------------------------------------------
// prep_all: all input conversions/transposes in ONE launch (range dispatch).
// ---------------------------------------------------------------------------
__device__ __forceinline__ void tr_body(
    const float* __restrict__ in, short* __restrict__ out,
    int K, int N, int bx, int by, int tid, float (*ts)[65])
{
    const int k0 = by * 64, n0 = bx * 64;
    const int r = tid >> 2, cb = (tid & 3) * 16;
    #pragma unroll
    for (int u = 0; u < 16; u += 4) {
        const float4 v = *(const float4*)(in + (size_t)(k0 + r) * N + n0 + cb + u);
        ts[r][cb + u] = v.x; ts[r][cb + u + 1] = v.y;
        ts[r][cb + u + 2] = v.z; ts[r][cb + u + 3] = v.w;
    }
    __syncthreads();
    #pragma unroll
    for (int p = 0; p < 4; p++) {
        const int wr_ = (tid >> 4) + p * 16;
        const int c   = (tid & 15) * 4;
        uint2 pk;
        pk.x = pack2(ts[c][wr_], ts[c + 1][wr_]);
        pk.y = pack2(ts[c + 2][wr_], ts[c + 3][wr_]);
        *(uint2*)(out + (size_t)(n0 + wr_) * K + k0 + c) = pk;
    }
}

__global__ __launch_bounds__(256) void prep_all(
    const float* __restrict__ mem, const float* __restrict__ cmem,
    const float* __restrict__ inp, short* __restrict__ catb,
    const float* __restrict__ pos, short* __restrict__ posb,
    const float* __restrict__ qkv_w, short* __restrict__ qkv_wt,
    const float* __restrict__ r_w, short* __restrict__ r_wt,
    const float* __restrict__ o_w, short* __restrict__ o_wt,
    const float* __restrict__ ff_w1, short* __restrict__ ff1t,
    const float* __restrict__ ff_w2, short* __restrict__ ff2t)
{
    __shared__ float ts[64][65];
    const int bid = blockIdx.x;
    const int tid = threadIdx.x;
    if (bid < 2560) {
        const int i = bid * 256 + tid;
        const int row = i >> 7, c = (i & 127) * 8;
        const float* src;
        if (row < 2048)      src = mem  + (size_t)row * 1024;
        else if (row < 3072) src = cmem + (size_t)(row - 2048) * 1024;
        else                 src = inp  + (size_t)(row - 3072) * 1024;
        const float4 a = *(const float4*)(src + c);
        const float4 b = *(const float4*)(src + c + 4);
        uint4 o;
        o.x = pack2(a.x, a.y); o.y = pack2(a.z, a.w);
        o.z = pack2(b.x, b.y); o.w = pack2(b.z, b.w);
        *(uint4*)(catb + (size_t)i * 8) = o;
    } else if (bid < 3840) {
        const int i = (bid - 2560) * 256 + tid;
        const float4 a = *(const float4*)(pos + (size_t)i * 8);
        const float4 b = *(const float4*)(pos + (size_t)i * 8 + 4);
        uint4 o;
        o.x = pack2(a.x, a.y); o.y = pack2(a.z, a.w);
        o.z = pack2(b.x, b.y); o.w = pack2(b.z, b.w);
        *(uint4*)(posb + (size_t)i * 8) = o;
    } else if (bid < 4608) {
        const int r = bid - 3840; tr_body(qkv_w, qkv_wt, 1024, 3072, r % 48, r / 48, tid, ts);
    } else if (bid < 4864) {
        const int r = bid - 4608; tr_body(r_w, r_wt, 1024, 1024, r % 16, r / 16, tid, ts);
    } else if (bid < 5120) {
        const int r = bid - 4864; tr_body(o_w, o_wt, 1024, 1024, r % 16, r / 16, tid, ts);
    } else if (bid < 6144) {
        const int r = bid - 5120; tr_body(ff_w1, ff1t, 1024, 4096, r % 64, r / 64, tid, ts);
    } else {
        const int r = bid - 6144; tr_body(ff_w2, ff2t, 4096, 1024, r % 16, r / 16, tid, ts);
    }
}

// whb V-part (key-major) -> vtb (BSZ*NH, DH, KLEN) key-minor. Grid (40, 32).
__global__ __launch_bounds__(256) void vt_conv(
    const short* __restrict__ wh, short* __restrict__ vt)
{
    __shared__ short Ts[64][72];
    const int j0 = blockIdx.x * 64;
    const int bn = blockIdx.y;
    const int b = bn >> 4, n = bn & 15;
    const int tid = threadIdx.x;
    {
        const int key = tid >> 2, c = (tid & 3) * 16;
        const short* p = wh + ((size_t)(j0 + key) * BSZ + b) * 3072 + 2048 + n * 64 + c;
        *(bf16x8*)&Ts[key][c]     = *(const bf16x8*)p;
        *(bf16x8*)&Ts[key][c + 8] = *(const bf16x8*)(p + 8);
    }
    __syncthreads();
    {
        const int d = tid >> 2, kc = (tid & 3) * 16;
        __attribute__((aligned(16))) short tmp[16];
        #pragma unroll
        for (int u = 0; u < 16; u++) tmp[u] = Ts[kc + u][d];
        short* q = vt + ((size_t)(bn * 64) + d) * KLEN + j0 + kc;
        *(uint4*)q       = *(uint4*)tmp;
        *(uint4*)(q + 8) = *((uint4*)tmp + 1);
    }
}

// ---------------------------------------------------------------------------
// m97 GEMM core, 2-phase pipelined (round-13 proven version): double-buffered
// LDS (32 KB -> 5 blocks/CU), next-tile global_load_lds issued BEFORE current
// ds_read+MFMA, ONE drain-barrier per K-step.
// ---------------------------------------------------------------------------
__device__ __forceinline__ void gemm_core(
    const short* __restrict__ A, const short* __restrict__ Bt,
    short* As, short* Bs, int Kfull, int klen, int bm, int bn,
    int tid, f32x4 acc[4][4])
{
    const int w  = tid >> 6;
    const int l  = tid & 63;
    const int lg = l >> 4, lc = l & 15;
    const int wr = w >> 1, wc = w & 1;
    const int srow = 2 * w * 16 + (l >> 2);
    const int scol = (l & 3) * 8;
    const size_t aoff0 = (size_t)(bm + srow) * Kfull + scol;
    const size_t boff0 = (size_t)(bn + srow) * Kfull + scol;
    const size_t rstep = (size_t)16 * Kfull;
    const int ch0 = 2 * w * 512, ch1 = (2 * w + 1) * 512;

    GLOAD16(A + aoff0, As + ch0);
    GLOAD16(A + aoff0 + rstep, As + ch1);
    GLOAD16(Bt + boff0, Bs + ch0);
    GLOAD16(Bt + boff0 + rstep, Bs + ch1);
    __syncthreads();

    int cur = 0;
    for (int k0 = 0; k0 < klen; k0 += 32) {
        const int nb = (cur ^ 1) * 4096;
        if (k0 + 32 < klen) {
            GLOAD16(A + aoff0 + k0 + 32, As + nb + ch0);
            GLOAD16(A + aoff0 + rstep + k0 + 32, As + nb + ch1);
            GLOAD16(Bt + boff0 + k0 + 32, Bs + nb + ch0);
            GLOAD16(Bt + boff0 + rstep + k0 + 32, Bs + nb + ch1);
        }
        const int cb = cur * 4096;
        bf16x8 af[4], bfr[4];
        #pragma unroll
        for (int m = 0; m < 4; m++)
            af[m] = *(const bf16x8*)(As + cb + (wr * 64 + m * 16 + lc) * 32 + lg * 8);
        #pragma unroll
        for (int n = 0; n < 4; n++)
            bfr[n] = *(const bf16x8*)(Bs + cb + (wc * 64 + n * 16 + lc) * 32 + lg * 8);
        #pragma unroll
        for (int m = 0; m < 4; m++)
            #pragma unroll
            for (int n = 0; n < 4; n++)
                acc[m][n] = __builtin_amdgcn_mfma_f32_16x16x32_bf16(
                    af[m], bfr[n], acc[m][n], 0, 0, 0);
        __syncthreads();
        cur ^= 1;
    }
}

// G1 (w_heads) + G2 (r_k) in one launch, XCD-swizzled (928 = 8*116).
__global__ __launch_bounds__(256) void gemm_g12(
    const short* __restrict__ catb, const short* __restrict__ qkv_wt,
    short* __restrict__ whb,
    const short* __restrict__ posb, const short* __restrict__ r_wt,
    short* __restrict__ rkb)
{
    __shared__ short As[8192], Bs[8192];
    const int tid = threadIdx.x;
    const int id0 = blockIdx.x;
    int id = (id0 & 7) * 116 + (id0 >> 3);   // XCD-group swizzle
    const short *A, *Bt; short* Cb; int N, bm, bn;
    if (id < 384) {
        A = catb; Bt = qkv_wt; Cb = whb; N = 3072;
        bm = (id >> 4) * 128; bn = (8 + (id & 15)) * 128;
    } else if (id < 768) {
        id -= 384;
        A = catb; Bt = qkv_wt; Cb = whb; N = 3072;
        bm = (24 + id / 24) * 128; bn = (id % 24) * 128;
    } else {
        id -= 768;
        A = posb; Bt = r_wt; Cb = rkb; N = 1024;
        bm = (id / 8) * 128; bn = (id % 8) * 128;
    }

    f32x4 acc[4][4];
    #pragma unroll
    for (int m = 0; m < 4; m++)
        #pragma unroll
        for (int n = 0; n < 4; n++) acc[m][n] = (f32x4){0.f, 0.f, 0.f, 0.f};
    gemm_core(A, Bt, As, Bs, 1024, 1024, bm, bn, tid, acc);

    const int w = tid >> 6, l = tid & 63, lg = l >> 4, lc = l & 15;
    const int wr = w >> 1, wc = w & 1;
    #pragma unroll
    for (int m = 0; m < 4; m++)
        #pragma unroll
        for (int n = 0; n < 4; n++) {
            const int col = bn + wc * 64 + n * 16 + lc;
            #pragma unroll
            for (int r = 0; r < 4; r++) {
                const int row = bm + wr * 64 + m * 16 + lg * 4 + r;
                Cb[(size_t)row * N + col] = f2bf(acc[m][n][r]);
            }
        }
}

// G7: h1 = relu(ares @ ff_w1 + b1), bf16 out. 1D grid, XCD-swizzled.
__global__ __launch_bounds__(256) void gemm_relu(
    const short* __restrict__ A, const short* __restrict__ Bt,
    const float* __restrict__ bias, short* __restrict__ Cb,
    int N, int K)
{
    __shared__ short As[8192], Bs[8192];
    const int tid = threadIdx.x;
    const int nbx = N >> 7;
    const int lid = blockIdx.x;
    const int nwg8 = gridDim.x >> 3;
    const int swz = (lid & 7) * nwg8 + (lid >> 3);
    const int bn = (swz % nbx) * 128, bm = (swz / nbx) * 128;
    f32x4 acc[4][4];
    #pragma unroll
    for (int m = 0; m < 4; m++)
        #pragma unroll
        for (int n = 0; n < 4; n++) acc[m][n] = (f32x4){0.f, 0.f, 0.f, 0.f};
    gemm_core(A, Bt, As, Bs, K, K, bm, bn, tid, acc);

    const int w = tid >> 6, l = tid & 63, lg = l >> 4, lc = l & 15;
    const int wr = w >> 1, wc = w & 1;
    #pragma unroll
    for (int m = 0; m < 4; m++)
        #pragma unroll
        for (int n = 0; n < 4; n++) {
            const int col = bn + wc * 64 + n * 16 + lc;
            const float bv = bias[col];
            #pragma unroll
            for (int r = 0; r < 4; r++) {
                const int row = bm + wr * 64 + m * 16 + lg * 4 + r;
                Cb[(size_t)row * N + col] = f2bf(fmaxf(acc[m][n][r] + bv, 0.0f));
            }
        }
}

// Split-K GEMM partial (1D grid, XCD-swizzled): z computes K-range
// [z*Ksub,(z+1)*Ksub) -> f32 partial C0/C1. nbx = N/128, nby = 16 (M=2048).
__global__ __launch_bounds__(256) void gemm_split(
    const short* __restrict__ A, const short* __restrict__ Bt,
    float* __restrict__ C0, float* __restrict__ C1,
    int N, int Kfull, int Ksub)
{
    __shared__ short As[8192], Bs[8192];
    const int tid = threadIdx.x;
    const int nbx = N >> 7;
    const int lid = blockIdx.x;
    const int nwg8 = gridDim.x >> 3;
    const int swz = (lid & 7) * nwg8 + (lid >> 3);
    const int bn = (swz % nbx) * 128;
    const int rest = swz / nbx;
    const int bm = (rest & 15) * 128;
    const int z = rest >> 4;
    float* C = z ? C1 : C0;
    f32x4 acc[4][4];
    #pragma unroll
    for (int m = 0; m < 4; m++)
        #pragma unroll
        for (int n = 0; n < 4; n++) acc[m][n] = (f32x4){0.f, 0.f, 0.f, 0.f};
    gemm_core(A + z * Ksub, Bt + z * Ksub, As, Bs, Kfull, Ksub, bm, bn, tid, acc);

    const int w = tid >> 6, l = tid & 63, lg = l >> 4, lc = l & 15;
    const int wr = w >> 1, wc = w & 1;
    #pragma unroll
    for (int m = 0; m < 4; m++)
        #pragma unroll
        for (int n = 0; n < 4; n++) {
            const int col = bn + wc * 64 + n * 16 + lc;
            #pragma unroll
            for (int r = 0; r < 4; r++) {
                const int row = bm + wr * 64 + m * 16 + lg * 4 + r;
                C[(size_t)row * N + col] = acc[m][n][r];
            }
        }
}

// ---------------------------------------------------------------------------
// MFMA flash attention — round-15 version (93 us), reverted verbatim.
// Round 16 proved the 5-shfl sh[5] gather was the round-12 regression culprit
// (extended cross-lane value lifetimes -> scratch spills, WRITE_SIZE 12 MB).
// The 8-shfl form keeps only 2 shuffled values live at a time and fits the
// register budget (VGPR 96, no spill).
// ---------------------------------------------------------------------------
__global__ __launch_bounds__(512, 2) void attn_mfma(
    const short* __restrict__ wh,   // (KLEN*BSZ, 3072) bf16
    const short* __restrict__ vt,   // (BSZ*NH, DH, KLEN) bf16
    const short* __restrict__ rk,   // (KLEN, NH*DH) bf16
    const float* __restrict__ rwb,
    const float* __restrict__ rrb,
    short* __restrict__ po,         // (2, 256, 128, 64) bf16
    float* __restrict__ ml)         // (2, 256, 128, 2) f32
{
    __shared__ __align__(16) short Ks[2][64 * 64];  // 16 KB dbuf
    __shared__ __align__(16) short Vs[2][64 * 64];  // 16 KB dbuf [d][key]
    __shared__ __align__(16) short Rs[256 * 64];    // 32 KB ring, slot = m & 255
    __shared__ __align__(16) short Ps[8][16 * 64];  // 16 KB

    const int bid = blockIdx.x;
    const int ibp = (bid >> 3) & 7;
    const int z   = (bid >> 6) & 1;
    const int bn  = ((bid & 7) << 2) | (bid >> 7);
    const int i0  = ibp * 128;
    const int b   = bn >> 4, n = bn & 15;
    const int tid = threadIdx.x;
    const int w   = tid >> 6;        // 0..7
    const int l   = tid & 63;
    const int lg  = l >> 4;
    const int lc  = l & 15;
    const int i_base = i0 + 16 * w;

    bf16x8 aqw[2], aqr[2];
    {
        const int i = i_base + lc;
        const short* qp = wh + ((size_t)(MTOT + i) * BSZ + b) * 3072 + n * 64;
        #pragma unroll
        for (int kc2 = 0; kc2 < 2; kc2++) {
            const bf16x8 q8 = *(const bf16x8*)(qp + kc2 * 32 + lg * 8);
            const int d0 = kc2 * 32 + lg * 8;
            #pragma unroll
            for (int e = 0; e < 8; e++) {
                const float qv = bf2f(q8[e]);
                aqw[kc2][e] = f2bf(qv + rwb[n * 64 + d0 + e]);
                aqr[kc2][e] = f2bf(qv + rrb[n * 64 + d0 + e]);
            }
        }
    }

    f32x4 o_acc[4];
    #pragma unroll
    for (int nt = 0; nt < 4; nt++) o_acc[nt] = (f32x4){0.f, 0.f, 0.f, 0.f};
    float mrun[4]  = {0.f, 0.f, 0.f, 0.f};
    float lpart[4] = {0.f, 0.f, 0.f, 0.f};

    const int jend   = i0 + 1664;
    const int jhalf  = i0 / 2 + 832;       // multiple of 64; z=0 range unmasked
    const int jstart = z ? jhalf : 0;
    const int jstop  = z ? jend  : jhalf;

    const int kr = tid >> 3, kc = tid & 7;
    const size_t whK = (size_t)b * 3072 + 1024 + n * 64;
    const size_t vtK = (size_t)(bn * 64) * KLEN;
    const int mbase0 = jstart - i0 + 896;

    // prologue: ring [mbase0,+192); buf0 K/V; prefetch tile 1
    #pragma unroll
    for (int u = 0; u < 3; u++) {
        const int m = mbase0 + kr + 64 * u;
        bf16x8 rv = (bf16x8){0, 0, 0, 0, 0, 0, 0, 0};
        if (m < KLEN)
            rv = *(const bf16x8*)(rk + (size_t)m * 1024 + n * 64 + kc * 8);
        const int slot = m & 255;
        *(bf16x8*)(Rs + slot * 64 + ((kc ^ (slot & 7)) * 8)) = rv;
    }
    {
        const bf16x8 k0 = *(const bf16x8*)(wh + (size_t)(jstart + kr) * (BSZ * 3072) + whK + kc * 8);
        const bf16x8 v0 = *(const bf16x8*)(vt + vtK + (size_t)kr * KLEN + jstart + kc * 8);
        *(bf16x8*)(Ks[0] + kr * 64 + ((kc ^ (kr & 7)) * 8)) = k0;
        *(bf16x8*)(Vs[0] + kr * 64 + ((kc ^ (kr & 7)) * 8)) = v0;
    }
    bf16x8 pk = (bf16x8){0,0,0,0,0,0,0,0}, pv = pk, pr;
    {
        const int jn = jstart + 64;
        if (jn < jstop) {
            pk = *(const bf16x8*)(wh + (size_t)(jn + kr) * (BSZ * 3072) + whK + kc * 8);
            pv = *(const bf16x8*)(vt + vtK + (size_t)kr * KLEN + jn + kc * 8);
        }
        const int m = mbase0 + 192 + kr;
        pr = (m < KLEN) ? *(const bf16x8*)(rk + (size_t)m * 1024 + n * 64 + kc * 8)
                        : (bf16x8){0, 0, 0, 0, 0, 0, 0, 0};
    }

    int cur = 0;
    for (int j0 = jstart; j0 < jstop; j0 += 64) {
        const int mbase = j0 - i0 + 896;
        __syncthreads();   // all waves done with tile t-1 reads; t's buf visible
        // ---- stage tile t+1 (writes disjoint from tile t's reads) ----
        *(bf16x8*)(Ks[cur ^ 1] + kr * 64 + ((kc ^ (kr & 7)) * 8)) = pk;
        *(bf16x8*)(Vs[cur ^ 1] + kr * 64 + ((kc ^ (kr & 7)) * 8)) = pv;
        {
            const int mw = mbase + 192 + kr;
            const int slot = mw & 255;
            *(bf16x8*)(Rs + slot * 64 + ((kc ^ (slot & 7)) * 8)) = pr;
        }
        // ---- prefetch tile t+2 ----
        {
            const int jn = j0 + 128;
            if (jn < jstop) {
                pk = *(const bf16x8*)(wh + (size_t)(jn + kr) * (BSZ * 3072) + whK + kc * 8);
                pv = *(const bf16x8*)(vt + vtK + (size_t)kr * KLEN + jn + kc * 8);
            }
            const int m = mbase + 256 + kr;
            pr = (m < KLEN) ? *(const bf16x8*)(rk + (size_t)m * 1024 + n * 64 + kc * 8)
                            : (bf16x8){0, 0, 0, 0, 0, 0, 0, 0};
        }

        // ---- AC = (Q+rwb) @ K^T ----
        __builtin_amdgcn_s_setprio(1);
        f32x4 sfr[4];
        #pragma unroll
        for (int jt = 0; jt < 4; jt++) {
            const int row = 16 * jt + lc;
            const int c0 = (lg ^ (row & 7)) * 8, c1 = ((4 + lg) ^ (row & 7)) * 8;
            const bf16x8 bk0 = *(const bf16x8*)(Ks[cur] + row * 64 + c0);
            const bf16x8 bk1 = *(const bf16x8*)(Ks[cur] + row * 64 + c1);
            f32x4 acc = (f32x4){0.f, 0.f, 0.f, 0.f};
            acc = __builtin_amdgcn_mfma_f32_16x16x32_bf16(aqw[0], bk0, acc, 0, 0, 0);
            acc = __builtin_amdgcn_mfma_f32_16x16x32_bf16(aqw[1], bk1, acc, 0, 0, 0);
            sfr[jt] = acc;
        }
        // ---- Dr = (Q+rrb) @ R^T (80-row window per wave, ring slots) ----
        f32x4 dr[5];
        #pragma unroll
        for (int mt = 0; mt < 5; mt++) {
            const int slot = (mbase + 16 * mt + lc + 112 - 16 * w) & 255;
            const int c0 = (lg ^ (slot & 7)) * 8, c1 = ((4 + lg) ^ (slot & 7)) * 8;
            const bf16x8 br0 = *(const bf16x8*)(Rs + slot * 64 + c0);
            const bf16x8 br1 = *(const bf16x8*)(Rs + slot * 64 + c1);
            f32x4 acc = (f32x4){0.f, 0.f, 0.f, 0.f};
            acc = __builtin_amdgcn_mfma_f32_16x16x32_bf16(aqr[0], br0, acc, 0, 0, 0);
            acc = __builtin_amdgcn_mfma_f32_16x16x32_bf16(aqr[1], br1, acc, 0, 0, 0);
            dr[mt] = acc;
        }
        __builtin_amdgcn_s_setprio(0);

        // ---- rel-shift gather + defer-max softmax ----
        #pragma unroll
        for (int r = 0; r < 4; r++) {
            const int q   = 4 * lg + r;
            const int o   = lc + 15 - q;
            const int src = (l & 48) | (o & 15);
            float sv[4];
            float mx = -1e30f;
            #pragma unroll
            for (int jt = 0; jt < 4; jt++) {
                const float v0 = __shfl(dr[jt][r], src);
                const float v1 = __shfl(dr[jt + 1][r], src);
                const float bd = (o < 16) ? v0 : v1;
                float s = (sfr[jt][r] + bd) * 0.125f;
                if (z) {
                    const int j = j0 + 16 * jt + lc;
                    if (j > i_base + q + MTOT) s = -1e30f;
                }
                sv[jt] = s;
                mx = fmaxf(mx, s);
            }
            if (__any(mx - mrun[r] > 8.0f)) {   // rare slow path
                #pragma unroll
                for (int msk = 1; msk <= 8; msk <<= 1)
                    mx = fmaxf(mx, __shfl_xor(mx, msk));
                const float mnew = fmaxf(mrun[r], mx);
                const float corr = __expf(mrun[r] - mnew);
                mrun[r] = mnew;
                lpart[r] *= corr;
                #pragma unroll
                for (int nt = 0; nt < 4; nt++) o_acc[nt][r] *= corr;
            }
            float p0 = __expf(sv[0] - mrun[r]);
            float p1 = __expf(sv[1] - mrun[r]);
            float p2 = __expf(sv[2] - mrun[r]);
            float p3 = __expf(sv[3] - mrun[r]);
            lpart[r] += (p0 + p1) + (p2 + p3);
            const unsigned pk01 = pack2(p0, p1);
            const unsigned pk23 = pack2(p2, p3);
            short* pw = Ps[w] + q * 64 + (lc & 7);
            const int qs = q & 7;
            pw[(((0 + (lc >> 3)) ^ qs) * 8)] = (short)(pk01 & 0xffffu);
            pw[(((2 + (lc >> 3)) ^ qs) * 8)] = (short)(pk01 >> 16);
            pw[(((4 + (lc >> 3)) ^ qs) * 8)] = (short)(pk23 & 0xffffu);
            pw[(((6 + (lc >> 3)) ^ qs) * 8)] = (short)(pk23 >> 16);
        }

        asm volatile("s_waitcnt lgkmcnt(0)" ::: "memory");
        __builtin_amdgcn_sched_barrier(0);

        // ---- O += P @ V ----
        __builtin_amdgcn_s_setprio(1);
        const int pc0 = (lg ^ (lc & 7)) * 8, pc1 = ((4 + lg) ^ (lc & 7)) * 8;
        const bf16x8 pa0 = *(const bf16x8*)(Ps[w] + lc * 64 + pc0);
        const bf16x8 pa1 = *(const bf16x8*)(Ps[w] + lc * 64 + pc1);
        #pragma unroll
        for (int nt = 0; nt < 4; nt++) {
            const int row = 16 * nt + lc;
            const int c0 = (lg ^ (row & 7)) * 8, c1 = ((4 + lg) ^ (row & 7)) * 8;
            const bf16x8 bv0 = *(const bf16x8*)(Vs[cur] + row * 64 + c0);
            const bf16x8 bv1 = *(const bf16x8*)(Vs[cur] + row * 64 + c1);
            o_acc[nt] = __builtin_amdgcn_mfma_f32_16x16x32_bf16(pa0, bv0, o_acc[nt], 0, 0, 0);
            o_acc[nt] = __builtin_amdgcn_mfma_f32_16x16x32_bf16(pa1, bv1, o_acc[nt], 0, 0, 0);
        }
        __builtin_amdgcn_s_setprio(0);
        cur ^= 1;
    }

    // ---- epilogue: reduce l once, write unnormalized partials ----
    const size_t blk = (size_t)z * 256 + ibp * 32 + bn;
    #pragma unroll
    for (int r = 0; r < 4; r++) {
        float lr = lpart[r];
        #pragma unroll
        for (int msk = 1; msk <= 8; msk <<= 1)
            lr += __shfl_xor(lr, msk);
        const int q = 16 * w + 4 * lg + r;    // 0..127
        #pragma unroll
        for (int nt = 0; nt < 4; nt++)
            po[(blk * 128 + q) * 64 + 16 * nt + lc] = f2bf(o_acc[nt][r]);
        if (lc == 0) {
            ml[(blk * 128 + q) * 2 + 0] = mrun[r];
            ml[(blk * 128 + q) * 2 + 1] = lr;
        }
    }
}

// Merge the two split-K partials -> attn_vec (bf16). Grid (512), 256 thr.
__global__ __launch_bounds__(256) void attn_merge(
    const short* __restrict__ po, const float* __restrict__ ml,
    short* __restrict__ av)
{
    const int blk = blockIdx.x;
    const int ib2 = blk >> 5, bn = blk & 31;
    const int b = bn >> 4, n = bn & 15;
    const int tid = threadIdx.x;
    const int q64 = tid >> 2, dc = (tid & 3) * 16;
    const int i = ib2 * 64 + q64;                       // global q row
    const size_t r0 = ((size_t)(i >> 7) * 32 + bn) * 128 + (i & 127);
    const size_t r1 = ((size_t)(256 + (i >> 7) * 32 + bn)) * 128 + (i & 127);
    const float m0 = ml[r0 * 2], l0 = ml[r0 * 2 + 1];
    const float m1 = ml[r1 * 2], l1 = ml[r1 * 2 + 1];
    const float M = fmaxf(m0, m1);
    const float c0 = __expf(m0 - M), c1 = __expf(m1 - M);
    const float invL = 1.0f / (l0 * c0 + l1 * c1);
    const bf16x8 a0 = *(const bf16x8*)(po + r0 * 64 + dc);
    const bf16x8 a1 = *(const bf16x8*)(po + r0 * 64 + dc + 8);
    const bf16x8 b0 = *(const bf16x8*)(po + r1 * 64 + dc);
    const bf16x8 b1 = *(const bf16x8*)(po + r1 * 64 + dc + 8);
    __attribute__((aligned(16))) short ov[16];
    #pragma unroll
    for (int e = 0; e < 8; e++) {
        ov[e]     = f2bf((bf2f(a0[e]) * c0 + bf2f(b0[e]) * c1) * invL);
        ov[e + 8] = f2bf((bf2f(a1[e]) * c0 + bf2f(b1[e]) * c1) * invL);
    }
    short* op = av + ((size_t)i * BSZ + b) * 1024 + n * 64 + dc;
    *(uint4*)op       = *(uint4*)ov;
    *(uint4*)(op + 8) = *((uint4*)ov + 1);
}

// ---------------------------------------------------------------------------
// Fused LayerNorm: out = LN(res + p0 + p1 (+ b2)) * scale + bias.
// OUTBF: 1 -> write bf16 only; 0 -> write f32 only.
// RESB:  residual source is bf16 (resb) instead of f32 (resf).
// ---------------------------------------------------------------------------
template <int OUTBF, bool HASB, bool RESB>
__global__ __launch_bounds__(256) void ln_fuse(
    const float* __restrict__ p0, const float* __restrict__ p1,
    const float* __restrict__ badd,
    const float* __restrict__ resf, const short* __restrict__ resb,
    const float* __restrict__ scale, const float* __restrict__ bias,
    float* __restrict__ outf, short* __restrict__ outb)
{
    const int row = blockIdx.x;
    const int tid = threadIdx.x;
    const size_t base = (size_t)row * 1024 + tid * 4;
    const float4 a = *(const float4*)(p0 + base);
    const float4 b = *(const float4*)(p1 + base);
    float rv[4];
    if (RESB) {
        const uint2 rr = *(const uint2*)(resb + base);
        rv[0] = bf2f((short)(rr.x & 0xffffu));
        rv[1] = bf2f((short)(rr.x >> 16));
        rv[2] = bf2f((short)(rr.y & 0xffffu));
        rv[3] = bf2f((short)(rr.y >> 16));
    } else {
        const float4 rf = *(const float4*)(resf + base);
        rv[0] = rf.x; rv[1] = rf.y; rv[2] = rf.z; rv[3] = rf.w;
    }
    float v[4] = {a.x + b.x + rv[0], a.y + b.y + rv[1],
                  a.z + b.z + rv[2], a.w + b.w + rv[3]};
    if (HASB) {
        const float4 bb = *(const float4*)(badd + tid * 4);
        v[0] += bb.x; v[1] += bb.y; v[2] += bb.z; v[3] += bb.w;
    }
    float s  = v[0] + v[1] + v[2] + v[3];
    float ss = v[0]*v[0] + v[1]*v[1] + v[2]*v[2] + v[3]*v[3];
    #pragma unroll
    for (int off = 32; off >= 1; off >>= 1) {
        s  += __shfl_down(s, off);
        ss += __shfl_down(ss, off);
    }
    __shared__ float red[8];
    const int lane = tid & 63, wid = tid >> 6;
    if (lane == 0) { red[wid] = s; red[4 + wid] = ss; }
    __syncthreads();
    if (tid == 0) {
        red[0] = red[0] + red[1] + red[2] + red[3];
        red[4] = red[4] + red[5] + red[6] + red[7];
    }
    __syncthreads();
    const float mean = red[0] * (1.0f / 1024.0f);
    const float var  = red[4] * (1.0f / 1024.0f) - mean * mean;
    const float rstd = rsqrtf(var + 1e-5f);
    const float4 sc = *(const float4*)(scale + tid * 4);
    const float4 bi = *(const float4*)(bias + tid * 4);
    float o0 = (v[0] - mean) * rstd * sc.x + bi.x;
    float o1 = (v[1] - mean) * rstd * sc.y + bi.y;
    float o2 = (v[2] - mean) * rstd * sc.z + bi.z;
    float o3 = (v[3] - mean) * rstd * sc.w + bi.w;
    if (OUTBF) {
        uint2 pk;
        pk.x = pack2(o0, o1);
        pk.y = pack2(o2, o3);
        *(uint2*)(outb + base) = pk;
    } else {
        *(float4*)(outf + base) = make_float4(o0, o1, o2, o3);
    }
}

// ---------------------------------------------------------------------------
extern "C" void kernel_launch(void* const* d_in, const int* in_sizes, int n_in,
                              void* d_out, int out_size, void* d_ws, size_t ws_size,
                              hipStream_t stream) {
    const float* input_ids = (const float*)d_in[0];
    const float* pos_emb   = (const float*)d_in[1];
    const float* mem       = (const float*)d_in[2];
    const float* c_mem     = (const float*)d_in[3];
    const float* qkv_w     = (const float*)d_in[5];
    const float* r_w       = (const float*)d_in[6];
    const float* o_w       = (const float*)d_in[7];
    const float* r_w_bias  = (const float*)d_in[8];
    const float* r_r_bias  = (const float*)d_in[9];
    const float* ln_a_s    = (const float*)d_in[10];
    const float* ln_a_b    = (const float*)d_in[11];
    const float* ff_w1     = (const float*)d_in[12];
    const float* ff_b1     = (const float*)d_in[13];
    const float* ff_w2     = (const float*)d_in[14];
    const float* ff_b2     = (const float*)d_in[15];
    const float* ln_f_s    = (const float*)d_in[16];
    const float* ln_f_b    = (const float*)d_in[17];

    char* base = (char*)d_ws;
    short* o_wt   = (short*)(base + 0);
    short* ff1t   = (short*)(base + 2097152);
    short* ff2t   = (short*)(base + 10485760);
    short* whb    = (short*)(base + 18874368);
    short* rkb    = (short*)(base + 50331648);
    short* qkv_wt = (short*)(base + 55574528);
    short* catb   = (short*)(base + 61865984);
    short* posb   = (short*)(base + 72351744);
    short* r_wt   = (short*)(base + 77594624);
    short* vtb    = (short*)(base + 55574528);
    short* po     = (short*)(base + 66060288);
    float* mlb    = (float*)(base + 74448896);
    short* avb    = (short*)(base + 74973184);
    float* hp0    = (float*)(base + 18874368);
    float* hp1    = (float*)(base + 27262976);
    short* aresb  = (short*)(base + 44040192);
    short* h1b    = (short*)(base + 48234496);

    const dim3 thr(256);

    prep_all<<<dim3(7168), thr, 0, stream>>>(
        mem, c_mem, input_ids, catb, pos_emb, posb,
        qkv_w, qkv_wt, r_w, r_wt, o_w, o_wt, ff_w1, ff1t, ff_w2, ff2t);
    gemm_g12<<<dim3(928), thr, 0, stream>>>(catb, qkv_wt, whb, posb, r_wt, rkb);
    vt_conv<<<dim3(40, 32), thr, 0, stream>>>(whb, vtb);
    attn_mfma<<<dim3(512), dim3(512), 0, stream>>>(
        whb, vtb, rkb, r_w_bias, r_r_bias, po, mlb);
    attn_merge<<<dim3(512), thr, 0, stream>>>(po, mlb, avb);
    gemm_split<<<dim3(256), thr, 0, stream>>>(
        avb, o_wt, hp0, hp1, 1024, 1024, 512);
    // attn_res = LN(input + hp0 + hp1) -> bf16 only
    ln_fuse<1, false, false><<<dim3(2048), thr, 0, stream>>>(
        hp0, hp1, nullptr, input_ids, nullptr, ln_a_s, ln_a_b, nullptr, aresb);
    gemm_relu<<<dim3(512), thr, 0, stream>>>(aresb, ff1t, ff_b1, h1b, 4096, 1024);
    gemm_split<<<dim3(256), thr, 0, stream>>>(
        h1b, ff2t, hp0, hp1, 1024, 4096, 2048);
    // out = LN(aresb + hp0 + hp1 + b2), residual from bf16
    ln_fuse<0, true, true><<<dim3(2048), thr, 0, stream>>>(
        hp0, hp1, ff_b2, nullptr, aresb, ln_f_s, ln_f_b, (float*)d_out, nullptr);
}